// Round 1
// baseline (643.003 us; speedup 1.0000x reference)
//
#include <hip/hip_runtime.h>
#include <hip/hip_bf16.h>

#define BB 32
#define CC 192
#define HH 64
#define WW 64
#define OO 192
#define EE 8
#define KTOT (CC*9)      // 1728
#define NSP (HH*WW)      // 4096
#define EWN (OO*CC*9)    // 331776 per expert

typedef __attribute__((ext_vector_type(8))) __bf16 bf16x8;
typedef __attribute__((ext_vector_type(4))) float f32x4;

// ---------------- kernel 1: global average pool ----------------
// grid = B*C blocks, 256 threads; each block reduces one (b,c) plane of 4096 floats
__global__ __launch_bounds__(256) void pool_kernel(const float* __restrict__ x,
                                                   float* __restrict__ pooled) {
    int bc = blockIdx.x;                       // 0..6143
    const float4* p4 = (const float4*)(x + (size_t)bc * NSP);
    int t = threadIdx.x;
    float s = 0.f;
#pragma unroll
    for (int i = 0; i < 4; ++i) {
        float4 v = p4[t + 256 * i];
        s += v.x + v.y + v.z + v.w;
    }
#pragma unroll
    for (int off = 32; off; off >>= 1) s += __shfl_down(s, off);
    __shared__ float red[4];
    int lane = t & 63, wv = t >> 6;
    if (lane == 0) red[wv] = s;
    __syncthreads();
    if (t == 0) pooled[bc] = (red[0] + red[1] + red[2] + red[3]) * (1.0f / 4096.0f);
}

// ---------------- kernel 2: routing = sigmoid(pooled @ rw^T + rb) ----------------
// 1 block, 256 threads: thread t -> (b = t>>3, e = t&7)
__global__ __launch_bounds__(256) void routing_kernel(const float* __restrict__ pooled,
                                                      const float* __restrict__ rw,
                                                      const float* __restrict__ rb,
                                                      float* __restrict__ routing) {
    int t = threadIdx.x;
    int b = t >> 3, e = t & 7;
    const float* pb = pooled + b * CC;
    const float* we = rw + e * CC;
    float acc = rb[e];
    for (int c = 0; c < CC; ++c) acc += pb[c] * we[c];
    routing[t] = 1.0f / (1.0f + expf(-acc));
}

// ---------------- kernel 3: mix expert weights -> bf16 ----------------
// wm[b][i] = sum_e routing[b,e] * ew[e,i];  i < 331776
__global__ __launch_bounds__(256) void mix_kernel(const float* __restrict__ ew,
                                                  const float* __restrict__ routing,
                                                  __bf16* __restrict__ wm) {
    __shared__ float r[BB * EE];
    int t = threadIdx.x;
    r[t] = routing[t];
    __syncthreads();
    size_t i = (size_t)blockIdx.x * 256 + t;   // exact: 1296*256 = 331776
    float w[EE];
#pragma unroll
    for (int e = 0; e < EE; ++e) w[e] = ew[(size_t)e * EWN + i];
#pragma unroll
    for (int b = 0; b < BB; ++b) {
        float acc = 0.f;
#pragma unroll
        for (int e = 0; e < EE; ++e) acc += r[b * EE + e] * w[e];
        wm[(size_t)b * EWN + i] = (__bf16)acc;
    }
}

// ---------------- kernel 4: implicit-GEMM conv via MFMA ----------------
// grid = (h=64, o_tile=3, b=32); block = 256 (4 waves), out tile 64(o) x 64(w)
__global__ __launch_bounds__(256) void conv_kernel(const float* __restrict__ x,
                                                   const __bf16* __restrict__ wm,
                                                   float* __restrict__ out) {
    const int h  = blockIdx.x;
    const int o0 = blockIdx.y * 64;
    const int b  = blockIdx.z;

    __shared__ __attribute__((aligned(16))) __bf16 As[64][40];   // [o][k] pad->80B stride
    __shared__ __attribute__((aligned(16))) __bf16 Bst[64][40];  // [w][k] (transposed)

    const int t = threadIdx.x;
    const int lane = t & 63;
    const int wv = t >> 6;
    const int wr = wv >> 1, wc = wv & 1;

    f32x4 acc[2][2] = {{{0.f,0.f,0.f,0.f},{0.f,0.f,0.f,0.f}},
                       {{0.f,0.f,0.f,0.f},{0.f,0.f,0.f,0.f}}};

    const __bf16* wmb = wm + (size_t)b * (size_t)(OO * KTOT);
    const float*  xb  = x + (size_t)b * (size_t)(CC * NSP);

    const int arow = t >> 2, apart = t & 3;    // A staging: 64 rows x 4x8 bf16
    const int bk = t >> 3, bs = t & 7;         // B staging: 32 k-rows x 8x8 w's

    const int l15 = lane & 15;
    const int lch = lane >> 4;

    for (int step = 0; step < 54; ++step) {
        const int k0 = step * 32;
        // ---- stage A tile [64][32] from mixed bf16 weights (contiguous) ----
        {
            const uint4 v = *(const uint4*)(wmb + (size_t)(o0 + arow) * KTOT + k0 + apart * 8);
            *(uint4*)(&As[arow][apart * 8]) = v;
        }
        // ---- stage B tile transposed: Bst[w][k] = x[b, c, h+kh-1, w+kw-1] ----
        {
            int k = k0 + bk;
            int c = k / 9, t9 = k % 9;
            int kh = t9 / 3, kw = t9 % 3;
            int hs = h + kh - 1;
            bool hok = ((unsigned)hs < (unsigned)HH);
            const float* xr = xb + ((size_t)c * HH + hs) * WW;
#pragma unroll
            for (int i = 0; i < 8; ++i) {
                int wdst = bs * 8 + i;
                int wsrc = wdst + kw - 1;
                float v = (hok && (unsigned)wsrc < (unsigned)WW) ? xr[wsrc] : 0.0f;
                Bst[wdst][bk] = (__bf16)v;
            }
        }
        __syncthreads();
        // ---- fragment loads + MFMA ----
        bf16x8 a0 = *(const bf16x8*)(&As[wr * 32 + l15     ][lch * 8]);
        bf16x8 a1 = *(const bf16x8*)(&As[wr * 32 + 16 + l15][lch * 8]);
        bf16x8 b0 = *(const bf16x8*)(&Bst[wc * 32 + l15     ][lch * 8]);
        bf16x8 b1 = *(const bf16x8*)(&Bst[wc * 32 + 16 + l15][lch * 8]);
        acc[0][0] = __builtin_amdgcn_mfma_f32_16x16x32_bf16(a0, b0, acc[0][0], 0, 0, 0);
        acc[0][1] = __builtin_amdgcn_mfma_f32_16x16x32_bf16(a0, b1, acc[0][1], 0, 0, 0);
        acc[1][0] = __builtin_amdgcn_mfma_f32_16x16x32_bf16(a1, b0, acc[1][0], 0, 0, 0);
        acc[1][1] = __builtin_amdgcn_mfma_f32_16x16x32_bf16(a1, b1, acc[1][1], 0, 0, 0);
        __syncthreads();
    }

    // ---- epilogue: D layout col = lane&15, row = (lane>>4)*4 + j ----
    float* ob = out + ((size_t)b * OO + o0) * NSP + h * WW;
    const int rowbase = wr * 32 + lch * 4;
    const int colbase = wc * 32 + l15;
#pragma unroll
    for (int m = 0; m < 2; ++m)
#pragma unroll
        for (int n = 0; n < 2; ++n)
#pragma unroll
            for (int j = 0; j < 4; ++j) {
                int o_local = rowbase + m * 16 + j;
                int col = colbase + n * 16;
                ob[(size_t)o_local * NSP + col] = acc[m][n][j];
            }
}

extern "C" void kernel_launch(void* const* d_in, const int* in_sizes, int n_in,
                              void* d_out, int out_size, void* d_ws, size_t ws_size,
                              hipStream_t stream) {
    const float* x  = (const float*)d_in[0];
    const float* ew = (const float*)d_in[1];
    const float* rw = (const float*)d_in[2];
    const float* rb = (const float*)d_in[3];
    float* out = (float*)d_out;

    char* ws = (char*)d_ws;
    float*  routing = (float*)(ws + 0);        // 1 KB
    float*  pooled  = (float*)(ws + 1024);     // 24 KB
    __bf16* wm      = (__bf16*)(ws + 25600);   // 32*331776*2 = ~20.3 MB

    hipLaunchKernelGGL(pool_kernel, dim3(BB * CC), dim3(256), 0, stream, x, pooled);
    hipLaunchKernelGGL(routing_kernel, dim3(1), dim3(256), 0, stream, pooled, rw, rb, routing);
    hipLaunchKernelGGL(mix_kernel, dim3(EWN / 256), dim3(256), 0, stream, ew, routing, wm);
    hipLaunchKernelGGL(conv_kernel, dim3(HH, OO / 64, BB), dim3(256), 0, stream, x, wm, out);
}

// Round 2
// 185.491 us; speedup vs baseline: 3.4665x; 3.4665x over previous
//
#include <hip/hip_runtime.h>
#include <hip/hip_bf16.h>

#define BB 32
#define CC 192
#define HH 64
#define WW 64
#define OO 192
#define EE 8
#define KTOT (CC*9)      // 1728
#define NSP (HH*WW)      // 4096
#define EWN (OO*CC*9)    // 331776 per expert

typedef __attribute__((ext_vector_type(8))) __bf16 bf16x8;
typedef __attribute__((ext_vector_type(4))) float f32x4;

// async global->LDS, 16B per lane. LDS dest must be wave-uniform base (lane*16 auto).
__device__ __forceinline__ void gl_lds16(const void* g, void* l) {
    __builtin_amdgcn_global_load_lds(
        (const __attribute__((address_space(1))) unsigned int*)g,
        (__attribute__((address_space(3))) unsigned int*)l, 16, 0, 0);
}

// ---------------- kernel 1: fused transpose (NCHW f32 -> NHWC bf16) + global avg pool ----
// grid = (3 c-tiles, 64 h, 32 b), 256 threads. Tile: 64 c x 64 w for one (b,h).
__global__ __launch_bounds__(256) void transpose_pool_kernel(const float* __restrict__ x,
                                                             __bf16* __restrict__ xT,
                                                             float* __restrict__ pooled) {
    const int ct = blockIdx.x, h = blockIdx.y, b = blockIdx.z;
    const int c0 = ct * 64;
    __shared__ float T[64][65];
    const int t = threadIdx.x;
    const int cr = t >> 2, wq = t & 3;     // 4 threads per c-row
    const float* xr = x + (((size_t)b * CC + c0 + cr) * HH + h) * WW;
    float ps = 0.f;
#pragma unroll
    for (int i = 0; i < 4; ++i) {
        float4 v = *(const float4*)(xr + (wq + i * 4) * 4);
        int wbase = (wq + i * 4) * 4;
        T[cr][wbase + 0] = v.x; T[cr][wbase + 1] = v.y;
        T[cr][wbase + 2] = v.z; T[cr][wbase + 3] = v.w;
        ps += v.x + v.y + v.z + v.w;
    }
    // reduce the 4 threads of this c-row, one atomic per (b,c)
    ps += __shfl_down(ps, 2);
    ps += __shfl_down(ps, 1);
    if (wq == 0) atomicAdd(pooled + b * CC + c0 + cr, ps);
    __syncthreads();
    // write transposed: row w (64 rows) x 64 c (128B) as bf16x8 chunks
#pragma unroll
    for (int i = 0; i < 2; ++i) {
        int u = t + 256 * i;
        int w = u >> 3, ch = u & 7;
        bf16x8 o;
#pragma unroll
        for (int j = 0; j < 8; ++j) o[j] = (__bf16)T[ch * 8 + j][w];
        *(bf16x8*)(xT + (((size_t)b * HH + h) * WW + w) * CC + c0 + ch * 8) = o;
    }
}

// ---------------- kernel 2: routing = sigmoid(mean @ rw^T + rb) ----------------
__global__ __launch_bounds__(256) void routing_kernel(const float* __restrict__ pooled,
                                                      const float* __restrict__ rw,
                                                      const float* __restrict__ rb,
                                                      float* __restrict__ routing) {
    int t = threadIdx.x;
    int b = t >> 3, e = t & 7;
    const float* pb = pooled + b * CC;
    const float* we = rw + e * CC;
    float acc = 0.f;
    for (int c = 0; c < CC; ++c) acc += pb[c] * we[c];
    acc = acc * (1.0f / 4096.0f) + rb[e];
    routing[t] = 1.0f / (1.0f + expf(-acc));
}

// ---------------- kernel 3: mix expert weights -> bf16, K-permuted ----------------
// dest layout: wmT[b][o][(kh*3+kw)*192 + c]; src i = (o*192+c)*9 + (kh*3+kw)
// one block per o: stage the contiguous 1728-float src window per expert in LDS.
__global__ __launch_bounds__(256) void mix_kernel(const float* __restrict__ ew,
                                                  const float* __restrict__ routing,
                                                  __bf16* __restrict__ wmT) {
    __shared__ float r[BB * EE];
    __shared__ float es[EE][KTOT];
    const int t = threadIdx.x;
    r[t] = routing[t];
    const int o = blockIdx.x;
    const size_t base = (size_t)o * KTOT;
#pragma unroll
    for (int e = 0; e < EE; ++e)
        for (int s = t; s < KTOT; s += 256)
            es[e][s] = ew[(size_t)e * EWN + base + s];
    __syncthreads();
    for (int i = 0; i < 7; ++i) {
        int jl = t + 256 * i;
        if (jl >= KTOT) break;
        int c = jl % 192;
        int t9 = jl / 192;
        int s = c * 9 + t9;
        float w[EE];
#pragma unroll
        for (int e = 0; e < EE; ++e) w[e] = es[e][s];
#pragma unroll
        for (int b = 0; b < BB; ++b) {
            float acc = 0.f;
#pragma unroll
            for (int e = 0; e < EE; ++e) acc += r[b * EE + e] * w[e];
            wmT[(size_t)b * EWN + base + jl] = (__bf16)acc;
        }
    }
}

// ---------------- kernel 4: NHWC implicit-GEMM conv via MFMA ----------------
// grid = (32 h-pairs, 3 o-tiles, 32 b); 256 threads (4 waves).
// Block tile: 64 o x 128 n (n = 2 h-rows x 64 w). K-loop: 27 steps of BK=64
// (k = (kh*3+kw)*192 + c, c innermost -> each step is one contiguous c-chunk
// at fixed (kh,kw), i.e. a shifted NHWC row: contiguous global 16B chunks).
// LDS: linear dest via global_load_lds + XOR-swizzled source/read (rule #21).
__global__ __launch_bounds__(256) void conv_kernel(const __bf16* __restrict__ xT,
                                                   const __bf16* __restrict__ wmT,
                                                   const __bf16* __restrict__ zp,
                                                   float* __restrict__ out) {
    const int h0 = blockIdx.x * 2;
    const int o0 = blockIdx.y * 64;
    const int b  = blockIdx.z;

    __shared__ __attribute__((aligned(128))) __bf16 As[64 * 64];    // [o][k] 128B rows
    __shared__ __attribute__((aligned(128))) __bf16 Bs[128 * 64];   // [n][k] 128B rows

    const int t = threadIdx.x;
    const int lane = t & 63;
    const int wv = t >> 6;
    const int wr = wv >> 1, wc = wv & 1;
    const int l15 = lane & 15, lch = lane >> 4;

    const int lrow = lane >> 3;                          // 0..7 within 8-row chunk
    const int offB = (((lane & 7) ^ lrow) << 4);         // pre-swizzled src byte offset

    f32x4 acc[2][4];
#pragma unroll
    for (int m = 0; m < 2; ++m)
#pragma unroll
        for (int n = 0; n < 4; ++n) acc[m][n] = (f32x4){0.f, 0.f, 0.f, 0.f};

    const char* wmb = (const char*)(wmT + (size_t)b * (OO * KTOT));
    const char* xtb = (const char*)(xT + (size_t)b * (HH * WW * CC));
    const char* zpb = (const char*)zp;

    const int hloc = wv >> 1;   // this wave stages B rows of h_local = wv>>1

    int step = 0;
    for (int kh = 0; kh < 3; ++kh) {
        for (int kw = 0; kw < 3; ++kw) {
            const int hp = h0 + hloc + kh - 1;
            const bool hok = (unsigned)hp < (unsigned)HH;
            for (int cc = 0; cc < 3; ++cc, ++step) {
                const int k0 = step * 64;
                const int c0 = cc * 64;
                // ---- stage A: 64 rows x 128B, wave rows [wv*16, +16) ----
#pragma unroll
                for (int inst = 0; inst < 2; ++inst) {
                    int row = wv * 16 + inst * 8;
                    const char* src = wmb + ((size_t)(o0 + row + lrow) * KTOT + k0) * 2 + offB;
                    gl_lds16(src, (void*)(As + row * 64));
                }
                // ---- stage B: 128 rows x 128B, wave rows [wv*32, +32) ----
#pragma unroll
                for (int inst = 0; inst < 4; ++inst) {
                    int row = wv * 32 + inst * 8;
                    int w = (row + lrow) & 63;
                    int wp = w + kw - 1;
                    bool ok = hok && ((unsigned)wp < (unsigned)WW);
                    const char* src = ok
                        ? xtb + (((size_t)hp * WW + wp) * CC + c0) * 2 + offB
                        : zpb + offB;
                    gl_lds16(src, (void*)(Bs + row * 64));
                }
                __syncthreads();
                // ---- fragments (swizzled ds_read_b128) + MFMA ----
                bf16x8 a[2][2], bf[4][2];
#pragma unroll
                for (int mi = 0; mi < 2; ++mi) {
                    int ar = wr * 32 + mi * 16 + l15;
#pragma unroll
                    for (int kc = 0; kc < 2; ++kc) {
                        int col = (kc * 64 + lch * 16) ^ ((ar & 7) << 4);
                        a[mi][kc] = *(const bf16x8*)((const char*)As + ar * 128 + col);
                    }
                }
#pragma unroll
                for (int ni = 0; ni < 4; ++ni) {
                    int br = wc * 64 + ni * 16 + l15;
#pragma unroll
                    for (int kc = 0; kc < 2; ++kc) {
                        int col = (kc * 64 + lch * 16) ^ ((br & 7) << 4);
                        bf[ni][kc] = *(const bf16x8*)((const char*)Bs + br * 128 + col);
                    }
                }
#pragma unroll
                for (int kc = 0; kc < 2; ++kc)
#pragma unroll
                    for (int mi = 0; mi < 2; ++mi)
#pragma unroll
                        for (int ni = 0; ni < 4; ++ni)
                            acc[mi][ni] = __builtin_amdgcn_mfma_f32_16x16x32_bf16(
                                a[mi][kc], bf[ni][kc], acc[mi][ni], 0, 0, 0);
                __syncthreads();
            }
        }
    }

    // ---- epilogue: D layout col = lane&15, row = (lane>>4)*4 + j ----
    float* ob = out + ((size_t)b * OO + o0) * NSP + (size_t)(h0 + wc) * WW;
#pragma unroll
    for (int mi = 0; mi < 2; ++mi)
#pragma unroll
        for (int ni = 0; ni < 4; ++ni)
#pragma unroll
            for (int j = 0; j < 4; ++j) {
                int orow = wr * 32 + mi * 16 + lch * 4 + j;
                int col = ni * 16 + l15;
                ob[(size_t)orow * NSP + col] = acc[mi][ni][j];
            }
}

extern "C" void kernel_launch(void* const* d_in, const int* in_sizes, int n_in,
                              void* d_out, int out_size, void* d_ws, size_t ws_size,
                              hipStream_t stream) {
    const float* x  = (const float*)d_in[0];
    const float* ew = (const float*)d_in[1];
    const float* rw = (const float*)d_in[2];
    const float* rb = (const float*)d_in[3];
    float* out = (float*)d_out;

    char* ws = (char*)d_ws;
    float*  routing = (float*)(ws + 0);           // 1 KB
    float*  pooled  = (float*)(ws + 4096);        // 24 KB
    __bf16* zp      = (__bf16*)(ws + 32768);      // 1 KB zero page
    __bf16* xT      = (__bf16*)(ws + 65536);      // 50,331,648 B
    __bf16* wmT     = (__bf16*)(ws + 65536 + 50331648);  // 21,233,664 B

    hipMemsetAsync(pooled, 0, BB * CC * sizeof(float), stream);
    hipMemsetAsync(zp, 0, 1024, stream);

    hipLaunchKernelGGL(transpose_pool_kernel, dim3(3, HH, BB), dim3(256), 0, stream,
                       x, xT, pooled);
    hipLaunchKernelGGL(routing_kernel, dim3(1), dim3(256), 0, stream,
                       pooled, rw, rb, routing);
    hipLaunchKernelGGL(mix_kernel, dim3(OO), dim3(256), 0, stream, ew, routing, wmT);
    hipLaunchKernelGGL(conv_kernel, dim3(HH / 2, OO / 64, BB), dim3(256), 0, stream,
                       xT, wmT, zp, out);
}

// Round 3
// 173.439 us; speedup vs baseline: 3.7074x; 1.0695x over previous
//
#include <hip/hip_runtime.h>
#include <hip/hip_bf16.h>

#define BB 32
#define CC 192
#define HH 64
#define WW 64
#define OO 192
#define EE 8
#define KTOT (CC*9)      // 1728
#define NSP (HH*WW)      // 4096
#define EWN (OO*CC*9)    // 331776 per expert

typedef __attribute__((ext_vector_type(8))) __bf16 bf16x8;
typedef __attribute__((ext_vector_type(4))) float f32x4;

// async global->LDS, 16B per lane (dest = wave-uniform base + lane*16)
__device__ __forceinline__ void gl_lds16(const void* g, void* l) {
    __builtin_amdgcn_global_load_lds(
        (const __attribute__((address_space(1))) unsigned int*)g,
        (__attribute__((address_space(3))) unsigned int*)l, 16, 0, 0);
}

// ---------------- kernel 1: fused transpose (NCHW f32 -> NHWC bf16) + global avg pool ----
__global__ __launch_bounds__(256) void transpose_pool_kernel(const float* __restrict__ x,
                                                             __bf16* __restrict__ xT,
                                                             float* __restrict__ pooled) {
    const int ct = blockIdx.x, h = blockIdx.y, b = blockIdx.z;
    const int c0 = ct * 64;
    __shared__ float T[64][65];
    const int t = threadIdx.x;
    const int cr = t >> 2, wq = t & 3;
    const float* xr = x + (((size_t)b * CC + c0 + cr) * HH + h) * WW;
    float ps = 0.f;
#pragma unroll
    for (int i = 0; i < 4; ++i) {
        float4 v = *(const float4*)(xr + (wq + i * 4) * 4);
        int wbase = (wq + i * 4) * 4;
        T[cr][wbase + 0] = v.x; T[cr][wbase + 1] = v.y;
        T[cr][wbase + 2] = v.z; T[cr][wbase + 3] = v.w;
        ps += v.x + v.y + v.z + v.w;
    }
    ps += __shfl_down(ps, 2);
    ps += __shfl_down(ps, 1);
    if (wq == 0) atomicAdd(pooled + b * CC + c0 + cr, ps);
    __syncthreads();
#pragma unroll
    for (int i = 0; i < 2; ++i) {
        int u = t + 256 * i;
        int w = u >> 3, ch = u & 7;
        bf16x8 o;
#pragma unroll
        for (int j = 0; j < 8; ++j) o[j] = (__bf16)T[ch * 8 + j][w];
        *(bf16x8*)(xT + (((size_t)b * HH + h) * WW + w) * CC + c0 + ch * 8) = o;
    }
}

// ---------------- kernel 2: routing = sigmoid(mean @ rw^T + rb) ----------------
__global__ __launch_bounds__(256) void routing_kernel(const float* __restrict__ pooled,
                                                      const float* __restrict__ rw,
                                                      const float* __restrict__ rb,
                                                      float* __restrict__ routing) {
    int t = threadIdx.x;
    int b = t >> 3, e = t & 7;
    const float* pb = pooled + b * CC;
    const float* we = rw + e * CC;
    float acc = 0.f;
    for (int c = 0; c < CC; ++c) acc += pb[c] * we[c];
    acc = acc * (1.0f / 4096.0f) + rb[e];
    routing[t] = 1.0f / (1.0f + expf(-acc));
}

// ---------------- kernel 3: mix expert weights -> bf16, K-permuted ----------------
// dest: wmT[b][o][(kh*3+kw)*192 + c]; src i = (o*192+c)*9 + (kh*3+kw)
// grid (192 o, 4 b-groups); each block: 8 batches, full 1728-k window via LDS.
__global__ __launch_bounds__(256) void mix_kernel(const float* __restrict__ ew,
                                                  const float* __restrict__ routing,
                                                  __bf16* __restrict__ wmT) {
    __shared__ float r[BB * EE];
    __shared__ float es[EE][KTOT];
    const int t = threadIdx.x;
    r[t] = routing[t];
    const int o = blockIdx.x;
    const int b0 = blockIdx.y * 8;
    const size_t base = (size_t)o * KTOT;
#pragma unroll
    for (int e = 0; e < EE; ++e)
        for (int s = t; s < KTOT; s += 256)
            es[e][s] = ew[(size_t)e * EWN + base + s];
    __syncthreads();
    for (int i = 0; i < 7; ++i) {
        int jl = t + 256 * i;
        if (jl >= KTOT) break;
        int c = jl % 192;
        int t9 = jl / 192;
        int s = c * 9 + t9;
        float w[EE];
#pragma unroll
        for (int e = 0; e < EE; ++e) w[e] = es[e][s];
#pragma unroll
        for (int bi = 0; bi < 8; ++bi) {
            int b = b0 + bi;
            float acc = 0.f;
#pragma unroll
            for (int e = 0; e < EE; ++e) acc += r[b * EE + e] * w[e];
            wmT[(size_t)b * EWN + base + jl] = (__bf16)acc;
        }
    }
}

// ---------------- kernel 4: NHWC implicit-GEMM conv via MFMA ----------------
// Block tile: 192(o) x 128(n = 2 h-rows x 64 w), BK=64, 512 threads (8 waves 4Mx2N).
// Double-buffered LDS (2 x 40 KB), depth-1 prefetch, counted vmcnt(5) before barrier.
#define Bb_M 192
#define Bb_N 128
#define ASZ (BB_A_ELEMS)
#define BB_A_ELEMS (192*64)
#define BB_B_ELEMS (128*64)
#define BUFE (BB_A_ELEMS + BB_B_ELEMS)   // 20480 bf16 = 40960 B

__global__ __launch_bounds__(512) void conv_kernel(const __bf16* __restrict__ xT,
                                                   const __bf16* __restrict__ wmT,
                                                   const __bf16* __restrict__ zp,
                                                   float* __restrict__ out) {
    extern __shared__ __bf16 smem[];   // 2 * BUFE elements = 80 KB

    // bijective XCD swizzle: each XCD gets 4 consecutive b x all 16 slots... (1024 % 8 == 0)
    const int gid = blockIdx.x;              // 0..1023
    const int nid = (gid & 7) * 128 + (gid >> 3);
    const int b  = nid >> 5;                 // 0..31
    const int h0 = (nid & 31) * 2;           // 0,2,..,62

    const int t = threadIdx.x;
    const int lane = t & 63;
    const int wv = t >> 6;                   // 0..7
    const int wr = wv >> 1;                  // 0..3 (M quadrant, 48 rows)
    const int wc = wv & 1;                   // 0..1 (N half, 64 cols)
    const int l15 = lane & 15, lch = lane >> 4;
    const int lrow = lane >> 3;              // 0..7
    const int offB = (((lane & 7) ^ lrow) << 4);   // pre-swizzled source byte offset

    const char* wmb = (const char*)(wmT + (size_t)b * (OO * KTOT));
    const char* xtb = (const char*)(xT + (size_t)b * (HH * WW * CC));
    const char* zpb = (const char*)zp;

    f32x4 acc[3][4];
#pragma unroll
    for (int mi = 0; mi < 3; ++mi)
#pragma unroll
        for (int ni = 0; ni < 4; ++ni) acc[mi][ni] = (f32x4){0.f, 0.f, 0.f, 0.f};

    auto STAGE = [&](int buf, int step) {
        const int t9 = step / 3;
        const int cc = step - t9 * 3;
        const int kh = t9 / 3;
        const int kw = t9 - kh * 3;
        const int c0 = cc * 64;
        __bf16* As = smem + buf * BUFE;
        __bf16* Bs = As + BB_A_ELEMS;
        const size_t kB = (size_t)step * 128;        // byte offset in wm row (64 bf16)
        // A: 24 KB = 24 chunks of 8 rows x 128 B; this wave: 3
#pragma unroll
        for (int i = 0; i < 3; ++i) {
            const int chunk = wv * 3 + i;
            const char* src = wmb + (size_t)(chunk * 8 + lrow) * (KTOT * 2) + kB + offB;
            gl_lds16(src, (void*)(As + chunk * 512));
        }
        // B: 16 KB = 16 chunks of 8 rows x 128 B; this wave: 2
#pragma unroll
        for (int i = 0; i < 2; ++i) {
            const int chunk = wv * 2 + i;
            const int row0 = chunk * 8;
            const int hl = row0 >> 6;
            const int w = (row0 & 63) + lrow;
            const int hp = h0 + hl + kh - 1;
            const int wp = w + kw - 1;
            const bool ok = ((unsigned)hp < (unsigned)HH) && ((unsigned)wp < (unsigned)WW);
            const char* src = ok
                ? xtb + ((size_t)(hp * WW + wp) * CC + c0) * 2 + offB
                : zpb + offB;
            gl_lds16(src, (void*)(Bs + chunk * 512));
        }
    };

    STAGE(0, 0);
    for (int step = 0; step < 27; ++step) {
        const int cur = step & 1;
        if (step + 1 < 27) {
            STAGE(cur ^ 1, step + 1);                       // 5 loads in flight for t+1
            asm volatile("s_waitcnt vmcnt(5)" ::: "memory"); // tile t's 5 landed
        } else {
            asm volatile("s_waitcnt vmcnt(0)" ::: "memory");
        }
        __builtin_amdgcn_s_barrier();
        __builtin_amdgcn_sched_barrier(0);

        const __bf16* As = smem + cur * BUFE;
        const __bf16* Bs = As + BB_A_ELEMS;
#pragma unroll
        for (int kc = 0; kc < 2; ++kc) {
            bf16x8 a[3], bbf[4];
#pragma unroll
            for (int mi = 0; mi < 3; ++mi) {
                const int r = wr * 48 + mi * 16 + l15;
                const int col = (kc * 64 + lch * 16) ^ ((r & 7) << 4);
                a[mi] = *(const bf16x8*)((const char*)As + r * 128 + col);
            }
#pragma unroll
            for (int ni = 0; ni < 4; ++ni) {
                const int r = wc * 64 + ni * 16 + l15;
                const int col = (kc * 64 + lch * 16) ^ ((r & 7) << 4);
                bbf[ni] = *(const bf16x8*)((const char*)Bs + r * 128 + col);
            }
            __builtin_amdgcn_s_setprio(1);
#pragma unroll
            for (int mi = 0; mi < 3; ++mi)
#pragma unroll
                for (int ni = 0; ni < 4; ++ni)
                    acc[mi][ni] = __builtin_amdgcn_mfma_f32_16x16x32_bf16(
                        a[mi], bbf[ni], acc[mi][ni], 0, 0, 0);
            __builtin_amdgcn_s_setprio(0);
        }
        __builtin_amdgcn_s_barrier();
        __builtin_amdgcn_sched_barrier(0);
    }

    // epilogue: D layout col = lane&15, row = (lane>>4)*4 + j
    float* ob = out + (size_t)b * OO * NSP + (size_t)(h0 + wc) * WW;
#pragma unroll
    for (int mi = 0; mi < 3; ++mi)
#pragma unroll
        for (int ni = 0; ni < 4; ++ni)
#pragma unroll
            for (int j = 0; j < 4; ++j) {
                const int o = wr * 48 + mi * 16 + lch * 4 + j;
                const int w = ni * 16 + l15;
                ob[(size_t)o * NSP + w] = acc[mi][ni][j];
            }
}

extern "C" void kernel_launch(void* const* d_in, const int* in_sizes, int n_in,
                              void* d_out, int out_size, void* d_ws, size_t ws_size,
                              hipStream_t stream) {
    const float* x  = (const float*)d_in[0];
    const float* ew = (const float*)d_in[1];
    const float* rw = (const float*)d_in[2];
    const float* rb = (const float*)d_in[3];
    float* out = (float*)d_out;

    char* ws = (char*)d_ws;
    float*  routing = (float*)(ws + 0);
    float*  pooled  = (float*)(ws + 4096);
    __bf16* zp      = (__bf16*)(ws + 32768);
    __bf16* xT      = (__bf16*)(ws + 65536);                 // 50,331,648 B
    __bf16* wmT     = (__bf16*)(ws + 65536 + 50331648);      // 21,233,664 B

    hipMemsetAsync(pooled, 0, BB * CC * sizeof(float), stream);
    hipMemsetAsync(zp, 0, 1024, stream);

    hipFuncSetAttribute((const void*)conv_kernel,
                        hipFuncAttributeMaxDynamicSharedMemorySize, 2 * BUFE * 2);

    hipLaunchKernelGGL(transpose_pool_kernel, dim3(3, HH, BB), dim3(256), 0, stream,
                       x, xT, pooled);
    hipLaunchKernelGGL(routing_kernel, dim3(1), dim3(256), 0, stream,
                       pooled, rw, rb, routing);
    hipLaunchKernelGGL(mix_kernel, dim3(OO, 4), dim3(256), 0, stream, ew, routing, wmT);
    hipLaunchKernelGGL(conv_kernel, dim3(32 * 32), dim3(512), 2 * BUFE * 2, stream,
                       xT, wmT, zp, out);
}